// Round 2
// baseline (1933.622 us; speedup 1.0000x reference)
//
#include <hip/hip_runtime.h>

#define DD 2048   // hidden dim (K of gemm1, N of gemm2)
#define FF 4096   // ffn dim
#define TT 4096   // tokens
#define NE 8      // experts

typedef unsigned int u32;
typedef unsigned short u16;
typedef __attribute__((ext_vector_type(4))) float f32x4;
typedef __attribute__((ext_vector_type(8))) short s16x8;
typedef __attribute__((ext_vector_type(4))) unsigned short u16x4;

__device__ __forceinline__ u16 f2bf(float f) {
  u32 u = __builtin_bit_cast(u32, f);
  u = u + 0x7fffu + ((u >> 16) & 1u);   // RNE (inputs are finite)
  return (u16)(u >> 16);
}

__device__ __forceinline__ void gload_lds16(const void* g, void* l) {
  __builtin_amdgcn_global_load_lds((const __attribute__((address_space(1))) u32*)g,
                                   (__attribute__((address_space(3))) u32*)l, 16, 0, 0);
}

// ---------------- pre-passes ----------------

__global__ __launch_bounds__(256) void cast_kernel(const float* __restrict__ X,
                                                   u16* __restrict__ Xb) {
  size_t i = (size_t)blockIdx.x * 256 + threadIdx.x;   // over T*D/4
  f32x4 v = ((const f32x4*)X)[i];
  u16x4 o;
  o[0] = f2bf(v[0]); o[1] = f2bf(v[1]); o[2] = f2bf(v[2]); o[3] = f2bf(v[3]);
  ((u16x4*)Xb)[i] = o;
}

__global__ __launch_bounds__(256) void router_kernel(const float* __restrict__ X,
                                                     const float* __restrict__ RW,
                                                     int* __restrict__ eid,
                                                     float* __restrict__ gate,
                                                     int* __restrict__ counts) {
  int w = threadIdx.x >> 6, l = threadIdx.x & 63;
  int t = blockIdx.x * 4 + w;
  const f32x4* xv = (const f32x4*)(X + (size_t)t * DD);
  float best = -1e30f; int be = 0;
  for (int e = 0; e < NE; ++e) {
    const f32x4* wv = (const f32x4*)(RW + (size_t)e * DD);
    float s = 0.f;
    #pragma unroll
    for (int i = 0; i < DD / 256; ++i) {           // 8 iters
      f32x4 a = xv[i * 64 + l], b = wv[i * 64 + l];
      s += a[0]*b[0] + a[1]*b[1] + a[2]*b[2] + a[3]*b[3];
    }
    #pragma unroll
    for (int off = 32; off; off >>= 1) s += __shfl_xor(s, off);
    if (s > best) { best = s; be = e; }            // strict > == top_k tie rule
  }
  if (l == 0) {
    eid[t] = be;
    gate[t] = 1.f / (1.f + expf(-best));
    atomicAdd(counts + be, 1);
  }
}

__global__ void scan_kernel(const int* __restrict__ counts, int* __restrict__ offs,
                            int* __restrict__ cursor) {
  if (threadIdx.x == 0) {
    int a = 0;
    for (int e = 0; e < NE; ++e) { offs[e] = a; cursor[e] = a; a += counts[e]; }
    offs[NE] = a;
  }
}

__global__ __launch_bounds__(256) void assign_kernel(const int* __restrict__ eid,
                                                     int* __restrict__ cursor,
                                                     int* __restrict__ tok_of) {
  int t = blockIdx.x * 256 + threadIdx.x;
  int p = atomicAdd(cursor + eid[t], 1);
  tok_of[p] = t;
}

__global__ __launch_bounds__(256) void gather_kernel(const float* __restrict__ X,
                                                     const int* __restrict__ tok_of,
                                                     const float* __restrict__ gate,
                                                     u16* __restrict__ Xs) {
  int p = blockIdx.x;
  int t = tok_of[p];
  float g = gate[t];
  const f32x4* src = (const f32x4*)(X + (size_t)t * DD);
  u16* dst = Xs + (size_t)p * DD;
  for (int i = threadIdx.x; i < DD / 4; i += 256) {
    f32x4 v = src[i];
    u16x4 o;
    o[0] = f2bf(v[0]*g); o[1] = f2bf(v[1]*g); o[2] = f2bf(v[2]*g); o[3] = f2bf(v[3]*g);
    *(u16x4*)(dst + i * 4) = o;
  }
}

// ---------------- GEMM1: h = silu(A@Wg) * (A@Wu), bf16 out ----------------
// A: bf16 [T][D] (expert-sorted or dense). W: fp32 [D][2F] ([gate|up]).
template<bool EXPERT>
__global__ __launch_bounds__(256) void gemm1_kernel(const u16* __restrict__ A,
                                                    const float* __restrict__ Wg,
                                                    u16* __restrict__ H,
                                                    const int* __restrict__ offs) {
  constexpr int BM = 128, BN = 64, BK = 32, BKP = 40;
  __shared__ __align__(16) u16 As[BM * BK];
  __shared__ __align__(16) u16 Bs[2][BN * BKP];

  int e = 0, m0 = 0, mcnt = TT;
  if (EXPERT) { e = blockIdx.z; m0 = offs[e]; mcnt = offs[e + 1] - m0; }
  int mt = blockIdx.y;
  if (mt * BM >= mcnt) return;
  m0 += mt * BM;
  mcnt = min(mcnt - mt * BM, BM);
  const int n0 = blockIdx.x * BN;
  const float* W = Wg + (size_t)e * DD * (2 * FF);

  const int tid = threadIdx.x;
  const int w = tid >> 6, l = tid & 63;
  const int wm = w >> 1, wn = w & 1;
  const int l16 = l & 15, lq = l >> 4;
  const int sl16 = tid & 15, skp = (tid >> 4) * 2;   // staging coords

  f32x4 ag[4][2], au[4][2];
  #pragma unroll
  for (int i = 0; i < 4; ++i)
    #pragma unroll
    for (int j = 0; j < 2; ++j) { ag[i][j] = (f32x4)0.f; au[i][j] = (f32x4)0.f; }

  for (int k0 = 0; k0 < DD; k0 += BK) {
    // stage A (bf16) via global_load_lds, linear [BM][BK]
    #pragma unroll
    for (int i = 0; i < 2; ++i) {
      int id = (w * 2 + i) * 64 + l;
      int row = id >> 2, ch = id & 3;
      int ar = row < mcnt ? row : mcnt - 1;
      gload_lds16(A + (size_t)(m0 + ar) * DD + k0 + ch * 8, (u16*)As + id * 8);
    }
    // stage B fp32->bf16, transposed [BN][BKP]
    #pragma unroll
    for (int hh = 0; hh < 2; ++hh) {
      const float* bp = W + (size_t)(k0 + skp) * (2 * FF) + (size_t)hh * FF + n0 + sl16 * 4;
      f32x4 r0 = *(const f32x4*)bp;
      f32x4 r1 = *(const f32x4*)(bp + 2 * FF);
      u16* bd = (u16*)Bs[hh];
      #pragma unroll
      for (int j = 0; j < 4; ++j) {
        u32 pk = (u32)f2bf(r0[j]) | ((u32)f2bf(r1[j]) << 16);
        *(u32*)(bd + (sl16 * 4 + j) * BKP + skp) = pk;
      }
    }
    __syncthreads();
    s16x8 af[4], bg[2], bu[2];
    #pragma unroll
    for (int mf = 0; mf < 4; ++mf)
      af[mf] = *(const s16x8*)(As + (wm * 64 + mf * 16 + l16) * BK + lq * 8);
    #pragma unroll
    for (int nf = 0; nf < 2; ++nf) {
      bg[nf] = *(const s16x8*)((u16*)Bs[0] + (wn * 32 + nf * 16 + l16) * BKP + lq * 8);
      bu[nf] = *(const s16x8*)((u16*)Bs[1] + (wn * 32 + nf * 16 + l16) * BKP + lq * 8);
    }
    #pragma unroll
    for (int mf = 0; mf < 4; ++mf)
      #pragma unroll
      for (int nf = 0; nf < 2; ++nf) {
        ag[mf][nf] = __builtin_amdgcn_mfma_f32_16x16x32_bf16(af[mf], bg[nf], ag[mf][nf], 0, 0, 0);
        au[mf][nf] = __builtin_amdgcn_mfma_f32_16x16x32_bf16(af[mf], bu[nf], au[mf][nf], 0, 0, 0);
      }
    __syncthreads();
  }
  #pragma unroll
  for (int mf = 0; mf < 4; ++mf) {
    #pragma unroll
    for (int r = 0; r < 4; ++r) {
      int row = wm * 64 + mf * 16 + lq * 4 + r;
      if (row < mcnt) {
        size_t base = (size_t)(m0 + row) * FF;
        #pragma unroll
        for (int nf = 0; nf < 2; ++nf) {
          float g = ag[mf][nf][r], u = au[mf][nf][r];
          float hv = g / (1.f + expf(-g)) * u;     // silu(g)*u
          H[base + n0 + wn * 32 + nf * 16 + l16] = f2bf(hv);
        }
      }
    }
  }
}

// ---------------- GEMM2: out = H @ Wd (scatter or += dense) ----------------
// H: bf16 [T][F]. Wd: fp32 [F][D].
template<bool EXPERT>
__global__ __launch_bounds__(256) void gemm2_kernel(const u16* __restrict__ Hh,
                                                    const float* __restrict__ Wd,
                                                    float* __restrict__ Out,
                                                    const int* __restrict__ offs,
                                                    const int* __restrict__ tok_of) {
  constexpr int BM = 128, BN = 128, BK = 32, BKP = 40;
  __shared__ __align__(16) u16 As[BM * BK];
  __shared__ __align__(16) u16 Bs[BN * BKP];

  int e = 0, m0 = 0, mcnt = TT;
  if (EXPERT) { e = blockIdx.z; m0 = offs[e]; mcnt = offs[e + 1] - m0; }
  int mt = blockIdx.y;
  if (mt * BM >= mcnt) return;
  m0 += mt * BM;
  mcnt = min(mcnt - mt * BM, BM);
  const int n0 = blockIdx.x * BN;
  const float* W = Wd + (size_t)e * FF * DD;

  const int tid = threadIdx.x;
  const int w = tid >> 6, l = tid & 63;
  const int wm = w >> 1, wn = w & 1;
  const int l16 = l & 15, lq = l >> 4;
  const int sl16 = tid & 15, skp = (tid >> 4) * 2;

  f32x4 acc[4][4];
  #pragma unroll
  for (int i = 0; i < 4; ++i)
    #pragma unroll
    for (int j = 0; j < 4; ++j) acc[i][j] = (f32x4)0.f;

  for (int k0 = 0; k0 < FF; k0 += BK) {
    #pragma unroll
    for (int i = 0; i < 2; ++i) {
      int id = (w * 2 + i) * 64 + l;
      int row = id >> 2, ch = id & 3;
      int ar = row < mcnt ? row : mcnt - 1;
      gload_lds16(Hh + (size_t)(m0 + ar) * FF + k0 + ch * 8, (u16*)As + id * 8);
    }
    #pragma unroll
    for (int nh = 0; nh < 2; ++nh) {
      const float* bp = W + (size_t)(k0 + skp) * DD + n0 + nh * 64 + sl16 * 4;
      f32x4 r0 = *(const f32x4*)bp;
      f32x4 r1 = *(const f32x4*)(bp + DD);
      #pragma unroll
      for (int j = 0; j < 4; ++j) {
        u32 pk = (u32)f2bf(r0[j]) | ((u32)f2bf(r1[j]) << 16);
        *(u32*)((u16*)Bs + (nh * 64 + sl16 * 4 + j) * BKP + skp) = pk;
      }
    }
    __syncthreads();
    s16x8 af[4], bf_[4];
    #pragma unroll
    for (int mf = 0; mf < 4; ++mf)
      af[mf] = *(const s16x8*)(As + (wm * 64 + mf * 16 + l16) * BK + lq * 8);
    #pragma unroll
    for (int nf = 0; nf < 4; ++nf)
      bf_[nf] = *(const s16x8*)((u16*)Bs + (wn * 64 + nf * 16 + l16) * BKP + lq * 8);
    #pragma unroll
    for (int mf = 0; mf < 4; ++mf)
      #pragma unroll
      for (int nf = 0; nf < 4; ++nf)
        acc[mf][nf] = __builtin_amdgcn_mfma_f32_16x16x32_bf16(af[mf], bf_[nf], acc[mf][nf], 0, 0, 0);
    __syncthreads();
  }
  #pragma unroll
  for (int mf = 0; mf < 4; ++mf) {
    #pragma unroll
    for (int r = 0; r < 4; ++r) {
      int row = wm * 64 + mf * 16 + lq * 4 + r;
      if (row >= mcnt) continue;
      size_t ob = EXPERT ? (size_t)tok_of[m0 + row] * DD : (size_t)(m0 + row) * DD;
      #pragma unroll
      for (int nf = 0; nf < 4; ++nf) {
        int col = n0 + wn * 64 + nf * 16 + l16;
        float v = acc[mf][nf][r];
        if (EXPERT) Out[ob + col] = v;      // first writer (top-1: each token once)
        else        Out[ob + col] += v;     // shared adds after (stream-ordered)
      }
    }
  }
}

// ---------------- launch ----------------

extern "C" void kernel_launch(void* const* d_in, const int* in_sizes, int n_in,
                              void* d_out, int out_size, void* d_ws, size_t ws_size,
                              hipStream_t stream) {
  const float* X   = (const float*)d_in[0];
  const float* RW  = (const float*)d_in[1];
  const float* WGU = (const float*)d_in[2];
  const float* WDN = (const float*)d_in[3];
  const float* SGU = (const float*)d_in[4];
  const float* SDN = (const float*)d_in[5];
  float* out = (float*)d_out;

  char* ws = (char*)d_ws;
  int*   counts = (int*)ws;              // 8 ints
  int*   cursor = (int*)(ws + 32);       // 8 ints
  int*   offs   = (int*)(ws + 64);       // 9 ints
  size_t o = 256;
  int*   eid  = (int*)(ws + o); o += (size_t)TT * 4;
  int*   tok  = (int*)(ws + o); o += (size_t)TT * 4;
  float* gate = (float*)(ws + o); o += (size_t)TT * 4;
  o = (o + 255) & ~(size_t)255;
  u16* xb = (u16*)(ws + o); o += (size_t)TT * DD * 2;
  u16* xs = (u16*)(ws + o); o += (size_t)TT * DD * 2;
  u16* hr = (u16*)(ws + o); o += (size_t)TT * FF * 2;
  u16* hs = hr;   // routed H fully consumed by gemm2<true> before gemm1<false> writes (stream order)
  if (o > ws_size) return;  // ws too small: fail loudly (output stays poisoned)

  hipMemsetAsync(ws, 0, 64, stream);
  cast_kernel<<<(TT * DD / 4) / 256, 256, 0, stream>>>(X, xb);
  router_kernel<<<TT / 4, 256, 0, stream>>>(X, RW, eid, gate, counts);
  scan_kernel<<<1, 64, 0, stream>>>(counts, offs, cursor);
  assign_kernel<<<TT / 256, 256, 0, stream>>>(eid, cursor, tok);
  gather_kernel<<<TT, 256, 0, stream>>>(X, tok, gate, xs);

  gemm1_kernel<true ><<<dim3(FF / 64, TT / 128, NE), 256, 0, stream>>>(xs, WGU, hr, offs);
  gemm2_kernel<true ><<<dim3(DD / 128, TT / 128, NE), 256, 0, stream>>>(hr, WDN, out, offs, tok);
  gemm1_kernel<false><<<dim3(FF / 64, TT / 128, 1 ), 256, 0, stream>>>(xb, SGU, hs, offs);
  gemm2_kernel<false><<<dim3(DD / 128, TT / 128, 1 ), 256, 0, stream>>>(hs, SDN, out, offs, tok);
}